// Round 5
// baseline (324.459 us; speedup 1.0000x reference)
//
#include <hip/hip_runtime.h>

typedef unsigned short u16;
typedef unsigned int u32;

typedef __attribute__((ext_vector_type(8)))  short bf16x8;
typedef __attribute__((ext_vector_type(4)))  float f32x4;

__device__ __forceinline__ float b2f(u16 u) {
    union { unsigned int i; float f; } v; v.i = ((unsigned int)u) << 16; return v.f;
}
__device__ __forceinline__ u16 f2b(float f) {
    union { float ff; unsigned int i; } v; v.ff = f;
    unsigned int x = v.i;
    return (u16)((x + 0x7fffu + ((x >> 16) & 1u)) >> 16);
}
__device__ __forceinline__ bool detect_bf16(const void* cosT) {
    // cos row 0 is all 1.0: fp32 word = 0x3F800000, bf16 pair = 0x3F803F80
    return ((*(const u32*)cosT) & 0xffffu) == 0x3f80u;
}
__device__ __forceinline__ float4 ld4(const void* p, size_t off, bool isbf) {
    if (isbf) {
        ushort4 v = *(const ushort4*)((const u16*)p + off);
        return make_float4(b2f(v.x), b2f(v.y), b2f(v.z), b2f(v.w));
    }
    return *(const float4*)((const float*)p + off);
}
__device__ __forceinline__ float lds1(const void* p, size_t off, bool isbf) {
    return isbf ? b2f(((const u16*)p)[off]) : ((const float*)p)[off];
}
// async 16B global -> LDS (dest = wave-uniform base + lane*16)
__device__ __forceinline__ void gll16(const void* g, void* l) {
    __builtin_amdgcn_global_load_lds(
        (const __attribute__((address_space(1))) u32*)g,
        (__attribute__((address_space(3))) u32*)l, 16, 0, 0);
}
// softcap + sliding-window mask. SCALING = 1/16, SOFTCAP = 50.
// masked -> -1e30, expf(-1e30) underflows to exactly 0.
__device__ __forceinline__ float capmask(float sdot, int i, int j) {
    float v = sdot * (0.0625f / 50.0f);
    v = fminf(fmaxf(v, -10.0f), 10.0f);
    float e = __expf(2.0f * v);
    float c = 50.0f * (e - 1.0f) / (e + 1.0f);
    bool allowed = (j <= i) && (j > i - 512);
    return allowed ? c : -1e30f;
}

// ---------------------------------------------------------------------------
// K0: prep = conv_hidden (blocks 0..2559) + weight transposes (2560..4159).
//   Hb[8192][640] bf16; WT[1536][640]; WoT[640][1024]
// ---------------------------------------------------------------------------
__global__ __launch_bounds__(256) void prep(
    const void* __restrict__ hidden,
    const void* __restrict__ Wq, const void* __restrict__ Wk,
    const void* __restrict__ Wv, const void* __restrict__ Wo,
    const void* __restrict__ cosT,
    u16* __restrict__ Hb, u16* __restrict__ WT, u16* __restrict__ WoT)
{
    const bool isbf = detect_bf16(cosT);
    __shared__ float T[32][33];
    int id = blockIdx.x;
    if (id < 2560) {
        size_t base = ((size_t)id * 256 + threadIdx.x) * 8;
        if (isbf) {
            *(uint4*)(Hb + base) = *(const uint4*)((const u16*)hidden + base);
        } else {
            float4 a = ld4(hidden, base, false);
            float4 b = ld4(hidden, base + 4, false);
            uint4 o;
            o.x = (u32)f2b(a.x) | ((u32)f2b(a.y) << 16);
            o.y = (u32)f2b(a.z) | ((u32)f2b(a.w) << 16);
            o.z = (u32)f2b(b.x) | ((u32)f2b(b.y) << 16);
            o.w = (u32)f2b(b.z) | ((u32)f2b(b.w) << 16);
            *(uint4*)(Hb + base) = o;
        }
        return;
    }
    id -= 2560;
    const int tx = threadIdx.x & 31, ty = threadIdx.x >> 5;
    if (id < 960) {
        const int n0 = (id % 48) * 32, k0 = (id / 48) * 32;
        const void* src; int ldw, nof;
        if (n0 < 1024)      { src = Wq; ldw = 1024; nof = n0; }
        else if (n0 < 1280) { src = Wk; ldw = 256;  nof = n0 - 1024; }
        else                { src = Wv; ldw = 256;  nof = n0 - 1280; }
#pragma unroll
        for (int j = 0; j < 4; j++)
            T[ty + 8 * j][tx] = lds1(src, (size_t)(k0 + ty + 8 * j) * ldw + nof + tx, isbf);
        __syncthreads();
#pragma unroll
        for (int j = 0; j < 4; j++)
            WT[(size_t)(n0 + ty + 8 * j) * 640 + k0 + tx] = f2b(T[tx][ty + 8 * j]);
    } else {
        id -= 960;
        const int k0 = (id & 31) * 32, n0 = (id >> 5) * 32;
#pragma unroll
        for (int j = 0; j < 4; j++)
            T[ty + 8 * j][tx] = lds1(Wo, (size_t)(k0 + ty + 8 * j) * 640 + n0 + tx, isbf);
        __syncthreads();
#pragma unroll
        for (int j = 0; j < 4; j++)
            WoT[(size_t)(n0 + ty + 8 * j) * 1024 + k0 + tx] = f2b(T[tx][ty + 8 * j]);
    }
}

// ---------------------------------------------------------------------------
// K1: QKV GEMM. 128x128 tile, BK=32, 4 waves, 16x16x32 MFMA.
// 2-phase double-buffered gll16 staging (one __syncthreads per tile; raw
// s_barrier version raced -- round 2). XCD-chunked swizzle: grid 768 = 8*96;
// XCD x owns 8 full m-panels x all 12 n -> per-XCD L2 set A 1.25M + B 1.9M
// fits 4M; A-panels fetched ~once from HBM (was ~8 XCDs each).
// V epilogue via transposed Sc tile -> 256B-coalesced stores (was scattered
// 8B at 8KB stride). LDS: dbuf 32 KB overlaid by epilogue Sc (33.8 KB).
// ---------------------------------------------------------------------------
__global__ __launch_bounds__(256) void qkv_gemm(
    const u16* __restrict__ Hb, const u16* __restrict__ WT,
    u16* __restrict__ Qb, u16* __restrict__ Kb, u16* __restrict__ Vtg)
{
    const int bid = blockIdx.x;
    const int sw = (bid & 7) * 96 + (bid >> 3);
    const int n0 = (sw % 12) * 128, m0 = (sw / 12) * 128;
    const int t = threadIdx.x, w = t >> 6, lane = t & 63;
    const int l15 = lane & 15, quad = lane >> 4;
    const int wm = (w & 1) * 64, wn = (w >> 1) * 64;

    __shared__ __align__(16) char smem[33792];   // A0@0 B0@8K A1@16K B1@24K | Sc overlay

    f32x4 acc[4][4];
#pragma unroll
    for (int i = 0; i < 4; i++)
#pragma unroll
        for (int j = 0; j < 4; j++) acc[i][j] = (f32x4)0.0f;

    // prologue: stage tile 0 into half 0
#pragma unroll
    for (int i = 0; i < 2; i++) {
        int ci = t + 256 * i, m = ci >> 2, c = ci & 3;
        gll16(Hb + (size_t)(m0 + m) * 640 + c * 8, smem + ci * 16);
        gll16(WT + (size_t)(n0 + m) * 640 + c * 8, smem + 8192 + ci * 16);
    }
    __syncthreads();

    for (int it = 0; it < 20; ++it) {
        const int kb = it * 32;
        char* cur = smem + (it & 1) * 16384;
        if (it < 19) {
            char* nxt = smem + ((it + 1) & 1) * 16384;
#pragma unroll
            for (int i = 0; i < 2; i++) {
                int ci = t + 256 * i, m = ci >> 2, c = ci & 3;
                gll16(Hb + (size_t)(m0 + m) * 640 + kb + 32 + c * 8, nxt + ci * 16);
                gll16(WT + (size_t)(n0 + m) * 640 + kb + 32 + c * 8, nxt + 8192 + ci * 16);
            }
        }
        const u16 (*Ah)[32] = (const u16 (*)[32])cur;
        const u16 (*Bh)[32] = (const u16 (*)[32])(cur + 8192);
        bf16x8 af[4], bfr[4];
#pragma unroll
        for (int mi = 0; mi < 4; mi++)
            af[mi] = *(const bf16x8*)&Ah[wm + mi * 16 + l15][quad * 8];
#pragma unroll
        for (int ni = 0; ni < 4; ni++)
            bfr[ni] = *(const bf16x8*)&Bh[wn + ni * 16 + l15][quad * 8];
#pragma unroll
        for (int mi = 0; mi < 4; mi++)
#pragma unroll
            for (int ni = 0; ni < 4; ni++)
                acc[mi][ni] = __builtin_amdgcn_mfma_f32_16x16x32_bf16(
                    af[mi], bfr[ni], acc[mi][ni], 0, 0, 0);
        __syncthreads();
    }

    u16 (*Sc)[132] = (u16 (*)[132])smem;
    if (n0 >= 1280) {
        // V region: transpose through Sc -> coalesced 256B row stores
        const int bb = m0 >> 12, sblk = m0 & 4095, vd0 = n0 - 1280;
#pragma unroll
        for (int mi = 0; mi < 4; mi++)
#pragma unroll
            for (int ni = 0; ni < 4; ni++)
#pragma unroll
                for (int r = 0; r < 4; r++)
                    Sc[wn + ni * 16 + l15][wm + mi * 16 + quad * 4 + r] = f2b(acc[mi][ni][r]);
        __syncthreads();
#pragma unroll
        for (int i = 0; i < 8; i++) {
            int idx = t + 256 * i, vd = idx >> 4, c = idx & 15;
            *(uint4*)(Vtg + (size_t)bb * 1048576 + (size_t)(vd0 + vd) * 4096 + sblk + c * 8) =
                *(const uint4*)&Sc[vd][c * 8];
        }
        return;
    }

    // Q/K epilogue: coalesced via Sc
#pragma unroll
    for (int mi = 0; mi < 4; mi++)
#pragma unroll
        for (int ni = 0; ni < 4; ni++)
#pragma unroll
            for (int r = 0; r < 4; r++)
                Sc[wm + mi * 16 + quad * 4 + r][wn + ni * 16 + l15] = f2b(acc[mi][ni][r]);
    __syncthreads();

    u16* dst; int ldo, coff;
    if (n0 < 1024) { dst = Qb; ldo = 1024; coff = n0; }
    else           { dst = Kb; ldo = 256;  coff = n0 - 1024; }
#pragma unroll
    for (int i = 0; i < 8; i++) {
        int idx = t + 256 * i, r = idx >> 4, c = idx & 15;
        *(uint4*)(dst + (size_t)(m0 + r) * ldo + coff + c * 8) = *(const uint4*)&Sc[r][c * 8];
    }
}

// ---------------------------------------------------------------------------
// K2: fused RMS-norm + RoPE in place on Kb ONLY (Q fused into attn).
// 4 rows/block (4 waves), grid 2048.
// ---------------------------------------------------------------------------
__global__ __launch_bounds__(256) void norm_rope_k(
    u16* __restrict__ Kb,
    const void* __restrict__ cosT, const void* __restrict__ sinT,
    const void* __restrict__ kw)
{
    const bool isbf = detect_bf16(cosT);
    const int row = blockIdx.x * 4 + (threadIdx.x >> 6), s = row & 4095;
    const int lane = threadIdx.x & 63, d0 = lane * 4;

    u16* p = Kb + (size_t)row * 256 + d0;

    ushort4 xv = *(const ushort4*)p;
    float x0 = b2f(xv.x), x1 = b2f(xv.y), x2 = b2f(xv.z), x3 = b2f(xv.w);
    float ssum = x0 * x0 + x1 * x1 + x2 * x2 + x3 * x3;
#pragma unroll
    for (int off = 32; off > 0; off >>= 1) ssum += __shfl_xor(ssum, off, 64);
    float rs = rsqrtf(ssum * (1.0f / 256.0f) + 1e-6f);

    float4 wv = ld4(kw, d0, isbf);
    float n0 = x0 * rs * (1.0f + wv.x);
    float n1 = x1 * rs * (1.0f + wv.y);
    float n2 = x2 * rs * (1.0f + wv.z);
    float n3 = x3 * rs * (1.0f + wv.w);

    float o0 = __shfl_xor(n0, 32, 64);
    float o1 = __shfl_xor(n1, 32, 64);
    float o2 = __shfl_xor(n2, 32, 64);
    float o3 = __shfl_xor(n3, 32, 64);
    float sgn = (lane < 32) ? -1.0f : 1.0f;

    float4 cv = ld4(cosT, (size_t)s * 256 + d0, isbf);
    float4 sv = ld4(sinT, (size_t)s * 256 + d0, isbf);
    *(ushort4*)p = make_ushort4(
        f2b(n0 * cv.x + sgn * o0 * sv.x), f2b(n1 * cv.y + sgn * o1 * sv.y),
        f2b(n2 * cv.z + sgn * o2 * sv.z), f2b(n3 * cv.w + sgn * o3 * sv.w));
}

// ---------------------------------------------------------------------------
// K3: sliding-window flash attention, 16x16x32 MFMA, KVBLK=64.
// Block = 8 waves = 4 heads x 2 q-halves = 32 queries. Q RMS-norm + RoPE
// FUSED at Q-load (each Q row consumed by exactly one block; rotate-half
// pair d<->d+128 = frag s<->s^4 SAME LANE; RMS cross-quad via shfl_xor 16/32).
// K/V staged per 64-key tile; LDS ~90 KB free at 1 block/CU (grid 256).
// XCD swizzle gives each XCD a contiguous 512-query span (K/V ~2 MB in L2).
// Fixed-max softmax (softcap bounds |s|<=50). P -> per-wave LDS -> B-operand
// of O^T = V^T P^T. 16x16 C/D: col=lane&15, row=(lane>>4)*4+reg.
// ---------------------------------------------------------------------------
__global__ __launch_bounds__(512, 2) void attn_mfma(
    const u16* __restrict__ Qb, const u16* __restrict__ Kb,
    const u16* __restrict__ Vtg,
    const void* __restrict__ cosT, const void* __restrict__ sinT,
    const void* __restrict__ qw,
    u16* __restrict__ AO)
{
    const int bx = blockIdx.x;                    // 0..127
    const int q0 = (((bx & 7) << 4) + (bx >> 3)) * 32;
    const int b  = blockIdx.y;
    const int t = threadIdx.x, w = t >> 6, lane = t & 63;
    const int h = w & 3, qh = w >> 2;
    const int l15 = lane & 15, quad = lane >> 4;
    const int qbase = q0 + qh * 16;
    const bool isbf = detect_bf16(cosT);

    __shared__ __align__(16) u16 Ks[64][264];
    __shared__ __align__(16) u16 Vt[256][72];
    __shared__ __align__(16) u16 Pr[8][16][72];
    __shared__ float l_s[8][16];

    // ---- Q load + fused RMS-norm + RoPE.
    // lane covers d = quad*8 + s8*32 + j (j=0..7) of row srow, head h.
    bf16x8 qf[8];
    {
        const int srow = qbase + l15;
        const u16* qp = Qb + ((size_t)(b * 4096 + srow)) * 1024 + h * 256 + quad * 8;
        float x[8][8];
        float ss = 0.f;
#pragma unroll
        for (int s8 = 0; s8 < 8; s8++) {
            ushort4 a = *(const ushort4*)(qp + s8 * 32);
            ushort4 c = *(const ushort4*)(qp + s8 * 32 + 4);
            x[s8][0] = b2f(a.x); x[s8][1] = b2f(a.y); x[s8][2] = b2f(a.z); x[s8][3] = b2f(a.w);
            x[s8][4] = b2f(c.x); x[s8][5] = b2f(c.y); x[s8][6] = b2f(c.z); x[s8][7] = b2f(c.w);
#pragma unroll
            for (int j = 0; j < 8; j++) ss += x[s8][j] * x[s8][j];
        }
        ss += __shfl_xor(ss, 16, 64);
        ss += __shfl_xor(ss, 32, 64);
        const float rs = rsqrtf(ss * (1.0f / 256.0f) + 1e-6f);
#pragma unroll
        for (int s8 = 0; s8 < 8; s8++) {
            const int d0 = quad * 8 + s8 * 32;
            float4 w0 = ld4(qw, d0, isbf), w1 = ld4(qw, d0 + 4, isbf);
            x[s8][0] *= rs * (1.0f + w0.x); x[s8][1] *= rs * (1.0f + w0.y);
            x[s8][2] *= rs * (1.0f + w0.z); x[s8][3] *= rs * (1.0f + w0.w);
            x[s8][4] *= rs * (1.0f + w1.x); x[s8][5] *= rs * (1.0f + w1.y);
            x[s8][6] *= rs * (1.0f + w1.z); x[s8][7] *= rs * (1.0f + w1.w);
        }
#pragma unroll
        for (int s8 = 0; s8 < 8; s8++) {
            const int d0 = quad * 8 + s8 * 32;
            const size_t co = (size_t)srow * 256 + d0;
            float4 c0 = ld4(cosT, co, isbf), c1 = ld4(cosT, co + 4, isbf);
            float4 s0 = ld4(sinT, co, isbf), s1 = ld4(sinT, co + 4, isbf);
            const float sgn = (s8 < 4) ? -1.0f : 1.0f;
            const int sp = s8 ^ 4;
            u16 r0 = f2b(x[s8][0] * c0.x + sgn * x[sp][0] * s0.x);
            u16 r1 = f2b(x[s8][1] * c0.y + sgn * x[sp][1] * s0.y);
            u16 r2 = f2b(x[s8][2] * c0.z + sgn * x[sp][2] * s0.z);
            u16 r3 = f2b(x[s8][3] * c0.w + sgn * x[sp][3] * s0.w);
            u16 r4 = f2b(x[s8][4] * c1.x + sgn * x[sp][4] * s1.x);
            u16 r5 = f2b(x[s8][5] * c1.y + sgn * x[sp][5] * s1.y);
            u16 r6 = f2b(x[s8][6] * c1.z + sgn * x[sp][6] * s1.z);
            u16 r7 = f2b(x[s8][7] * c1.w + sgn * x[sp][7] * s1.w);
            short rr[8] = {(short)r0, (short)r1, (short)r2, (short)r3,
                           (short)r4, (short)r5, (short)r6, (short)r7};
            qf[s8] = *(const bf16x8*)rr;
        }
    }

    f32x4 o[16];
#pragma unroll
    for (int i = 0; i < 16; i++) o[i] = (f32x4)0.0f;
    float lp[4] = {0.f, 0.f, 0.f, 0.f};

    const int lo = q0 - 511;
    const int jb0 = lo > 0 ? (lo >> 6) << 6 : 0;
    const int jb1 = (q0 + 31) & ~63;

    const u16* kbase = Kb + (size_t)b * 4096 * 256;
    const u16* vbase = Vtg + (size_t)b * 1048576;

    for (int jb = jb0; jb <= jb1; jb += 64) {
        __syncthreads();
        // stage K [64 keys][256 d] and Vt [256 d][64 keys], shared by 8 waves
#pragma unroll
        for (int i = 0; i < 4; i++) {
            int ci = t + 512 * i;
            *(uint4*)&Ks[ci >> 5][(ci & 31) * 8] =
                *(const uint4*)(kbase + (size_t)(jb + (ci >> 5)) * 256 + (ci & 31) * 8);
            *(uint4*)&Vt[ci >> 3][(ci & 7) * 8] =
                *(const uint4*)(vbase + (size_t)(ci >> 3) * 4096 + jb + (ci & 7) * 8);
        }
        __syncthreads();

        // ---- S = Q K^T : 16 queries x 64 keys (4 accs of 16x16)
        f32x4 s[4];
#pragma unroll
        for (int a = 0; a < 4; a++) s[a] = (f32x4)0.0f;
#pragma unroll
        for (int ds = 0; ds < 8; ds++) {
#pragma unroll
            for (int a = 0; a < 4; a++) {
                bf16x8 kf = *(const bf16x8*)&Ks[a * 16 + l15][ds * 32 + quad * 8];
                s[a] = __builtin_amdgcn_mfma_f32_16x16x32_bf16(qf[ds], kf, s[a], 0, 0, 0);
            }
        }
        // ---- softcap + mask + exp (fixed max), P -> LDS
        // accumulate lp in pairs (a=0,1 then a=2,3) = same fp order as 32-key tiles
#pragma unroll
        for (int ap = 0; ap < 2; ap++) {
            const int j0 = jb + ap * 32 + l15;
#pragma unroll
            for (int r = 0; r < 4; r++) {
                int qi = qbase + quad * 4 + r;
                float p0 = __expf(capmask(s[2 * ap][r],     qi, j0));
                float p1 = __expf(capmask(s[2 * ap + 1][r], qi, j0 + 16));
                u16 pb0 = f2b(p0), pb1 = f2b(p1);
                Pr[w][quad * 4 + r][ap * 32 + l15]      = pb0;
                Pr[w][quad * 4 + r][ap * 32 + 16 + l15] = pb1;
                lp[r] += b2f(pb0) + b2f(pb1);
            }
        }
        __threadfence_block();
        // ---- O^T += V^T P^T (two 32-k slices, same order as two old tiles)
        bf16x8 pf0 = *(const bf16x8*)&Pr[w][l15][quad * 8];
        bf16x8 pf1 = *(const bf16x8*)&Pr[w][l15][32 + quad * 8];
#pragma unroll
        for (int mt = 0; mt < 16; mt++) {
            bf16x8 vf0 = *(const bf16x8*)&Vt[mt * 16 + l15][quad * 8];
            o[mt] = __builtin_amdgcn_mfma_f32_16x16x32_bf16(vf0, pf0, o[mt], 0, 0, 0);
        }
#pragma unroll
        for (int mt = 0; mt < 16; mt++) {
            bf16x8 vf1 = *(const bf16x8*)&Vt[mt * 16 + l15][32 + quad * 8];
            o[mt] = __builtin_amdgcn_mfma_f32_16x16x32_bf16(vf1, pf1, o[mt], 0, 0, 0);
        }
    }

    // ---- l reduction across the 16 key-lanes
#pragma unroll
    for (int r = 0; r < 4; r++) {
        float v = lp[r];
        v += __shfl_xor(v, 1, 64); v += __shfl_xor(v, 2, 64);
        v += __shfl_xor(v, 4, 64); v += __shfl_xor(v, 8, 64);
        lp[r] = v;
    }
    if (l15 == 0) {
#pragma unroll
        for (int r = 0; r < 4; r++) l_s[w][quad * 4 + r] = lp[r];
    }
    __threadfence_block();
    __syncthreads();
    const float inv = 1.0f / l_s[w][l15];

    u16* aop = AO + ((size_t)(b * 4096 + qbase + l15)) * 1024 + h * 256 + quad * 4;
#pragma unroll
    for (int mt = 0; mt < 16; mt++) {
        *(ushort4*)(aop + mt * 16) = make_ushort4(
            f2b(o[mt][0] * inv), f2b(o[mt][1] * inv),
            f2b(o[mt][2] * inv), f2b(o[mt][3] * inv));
    }
}

// ---------------------------------------------------------------------------
// K4: output projection. BM=128, BN=64, grid 640 = 8*80 XCD-chunked swizzle
// (XCD owns 8 m-panels x all 10 n -> AO panels fetched ~once; 3.3 MB/L2).
// 2-phase dbuf staging (one __syncthreads per tile); dbuf 24 KB overlaid by
// Scf (34.8 KB).
// ---------------------------------------------------------------------------
__global__ __launch_bounds__(256) void out_gemm(
    const u16* __restrict__ AO, const u16* __restrict__ WoT,
    const void* __restrict__ cosT, void* __restrict__ outp)
{
    const bool isbf = detect_bf16(cosT);
    const int bid = blockIdx.x;
    const int sw = (bid & 7) * 80 + (bid >> 3);
    const int n0 = (sw % 10) * 64, m0 = (sw / 10) * 128;
    const int t = threadIdx.x, w = t >> 6, lane = t & 63;
    const int l15 = lane & 15, quad = lane >> 4;
    const int wm = (w & 1) * 64, wn = (w >> 1) * 32;

    __shared__ __align__(16) char smem[34816];   // A0@0 B0@8K A1@12K B1@20K | Scf overlay

    f32x4 acc[4][2];
#pragma unroll
    for (int i = 0; i < 4; i++)
#pragma unroll
        for (int j = 0; j < 2; j++) acc[i][j] = (f32x4)0.0f;

    // prologue: stage tile 0 into half 0
    {
#pragma unroll
        for (int i = 0; i < 2; i++) {
            int ci = t + 256 * i, m = ci >> 2, c = ci & 3;
            gll16(AO + (size_t)(m0 + m) * 1024 + c * 8, smem + ci * 16);
        }
        int m = t >> 2, c = t & 3;
        gll16(WoT + (size_t)(n0 + m) * 1024 + c * 8, smem + 8192 + t * 16);
    }
    __syncthreads();

    for (int it = 0; it < 32; ++it) {
        const int kb = it * 32;
        char* cur = smem + (it & 1) * 12288;
        if (it < 31) {
            char* nxt = smem + ((it + 1) & 1) * 12288;
#pragma unroll
            for (int i = 0; i < 2; i++) {
                int ci = t + 256 * i, m = ci >> 2, c = ci & 3;
                gll16(AO + (size_t)(m0 + m) * 1024 + kb + 32 + c * 8, nxt + ci * 16);
            }
            int m = t >> 2, c = t & 3;
            gll16(WoT + (size_t)(n0 + m) * 1024 + kb + 32 + c * 8, nxt + 8192 + t * 16);
        }
        const u16 (*Ah)[32] = (const u16 (*)[32])cur;
        const u16 (*Bh)[32] = (const u16 (*)[32])(cur + 8192);
        bf16x8 af[4], bfr[2];
#pragma unroll
        for (int mi = 0; mi < 4; mi++)
            af[mi] = *(const bf16x8*)&Ah[wm + mi * 16 + l15][quad * 8];
#pragma unroll
        for (int ni = 0; ni < 2; ni++)
            bfr[ni] = *(const bf16x8*)&Bh[wn + ni * 16 + l15][quad * 8];
#pragma unroll
        for (int mi = 0; mi < 4; mi++)
#pragma unroll
            for (int ni = 0; ni < 2; ni++)
                acc[mi][ni] = __builtin_amdgcn_mfma_f32_16x16x32_bf16(
                    af[mi], bfr[ni], acc[mi][ni], 0, 0, 0);
        __syncthreads();
    }

    float (*Scf)[68] = (float (*)[68])smem;
#pragma unroll
    for (int mi = 0; mi < 4; mi++)
#pragma unroll
        for (int ni = 0; ni < 2; ni++)
#pragma unroll
            for (int r = 0; r < 4; r++)
                Scf[wm + mi * 16 + quad * 4 + r][wn + ni * 16 + l15] = acc[mi][ni][r];
    __syncthreads();

    if (isbf) {
#pragma unroll
        for (int i = 0; i < 4; i++) {
            int idx = t + 256 * i, r = idx >> 3, c = idx & 7;   // 128 rows x 8 chunks(8 cols)
            ushort4 lo4 = make_ushort4(
                f2b(Scf[r][c * 8 + 0]), f2b(Scf[r][c * 8 + 1]),
                f2b(Scf[r][c * 8 + 2]), f2b(Scf[r][c * 8 + 3]));
            ushort4 hi4 = make_ushort4(
                f2b(Scf[r][c * 8 + 4]), f2b(Scf[r][c * 8 + 5]),
                f2b(Scf[r][c * 8 + 6]), f2b(Scf[r][c * 8 + 7]));
            u16* p = (u16*)outp + (size_t)(m0 + r) * 640 + n0 + c * 8;
            *(ushort4*)p = lo4; *(ushort4*)(p + 4) = hi4;
        }
    } else {
#pragma unroll
        for (int i = 0; i < 8; i++) {
            int idx = t + 256 * i, r = idx >> 4, c = idx & 15;  // 128 rows x 16 chunks(4 cols)
            float4 v = *(const float4*)&Scf[r][c * 4];
            *(float4*)((float*)outp + (size_t)(m0 + r) * 640 + n0 + c * 4) = v;
        }
    }
}

// ---------------------------------------------------------------------------
// Launch. Inputs: 0 hidden, 1 cos, 2 sin, 3 mask(UNUSED), 4 Wq, 5 Wk, 6 Wv,
// 7 Wo, 8 q_norm_w, 9 k_norm_w. Workspace (43.3 MB, AO overlays Hb+WT):
//   [0, 16.78M): Hb(10.49M) + WT(1.97M)  -- dead after GEMMs; AO reuses @0
//   [16.78M): WoT 1.31M | Qb 16.78M | Kb 4.19M | Vt_g 4.19M
// ---------------------------------------------------------------------------
extern "C" void kernel_launch(void* const* d_in, const int* in_sizes, int n_in,
                              void* d_out, int out_size, void* d_ws, size_t ws_size,
                              hipStream_t stream) {
    const void* hidden = d_in[0];
    const void* cosT   = d_in[1];
    const void* sinT   = d_in[2];
    const void* Wq     = d_in[4];
    const void* Wk     = d_in[5];
    const void* Wv     = d_in[6];
    const void* Wo     = d_in[7];
    const void* qw     = d_in[8];
    const void* kw     = d_in[9];

    char* ws = (char*)d_ws;
    u16* Hb  = (u16*)ws;                            // 8192*640
    u16* WT  = (u16*)(ws + 10485760);               // 1536*640
    u16* AO  = (u16*)ws;                            // 8192*1024 (overlays Hb/WT)
    u16* WoT = (u16*)(ws + 16777216);               // 640*1024
    u16* Qb  = (u16*)(ws + 18087936);               // 8192*1024
    u16* Kb  = (u16*)(ws + 34865152);               // 8192*256
    u16* Vtg = (u16*)(ws + 39059456);               // 2*256*4096

    prep<<<dim3(4160), 256, 0, stream>>>(hidden, Wq, Wk, Wv, Wo, cosT, Hb, WT, WoT);
    qkv_gemm<<<dim3(768), 256, 0, stream>>>(Hb, WT, Qb, Kb, Vtg);
    norm_rope_k<<<dim3(2048), 256, 0, stream>>>(Kb, cosT, sinT, kw);
    attn_mfma<<<dim3(128, 2), 512, 0, stream>>>(Qb, Kb, Vtg, cosT, sinT, qw, AO);
    out_gemm<<<dim3(640), 256, 0, stream>>>(AO, WoT, cosT, d_out);
}

// Round 6
// 310.288 us; speedup vs baseline: 1.0457x; 1.0457x over previous
//
#include <hip/hip_runtime.h>

typedef unsigned short u16;
typedef unsigned int u32;

typedef __attribute__((ext_vector_type(8)))  short bf16x8;
typedef __attribute__((ext_vector_type(4)))  float f32x4;

__device__ __forceinline__ float b2f(u16 u) {
    union { unsigned int i; float f; } v; v.i = ((unsigned int)u) << 16; return v.f;
}
__device__ __forceinline__ u16 f2b(float f) {
    union { float ff; unsigned int i; } v; v.ff = f;
    unsigned int x = v.i;
    return (u16)((x + 0x7fffu + ((x >> 16) & 1u)) >> 16);
}
__device__ __forceinline__ bool detect_bf16(const void* cosT) {
    // cos row 0 is all 1.0: fp32 word = 0x3F800000, bf16 pair = 0x3F803F80
    return ((*(const u32*)cosT) & 0xffffu) == 0x3f80u;
}
__device__ __forceinline__ float4 ld4(const void* p, size_t off, bool isbf) {
    if (isbf) {
        ushort4 v = *(const ushort4*)((const u16*)p + off);
        return make_float4(b2f(v.x), b2f(v.y), b2f(v.z), b2f(v.w));
    }
    return *(const float4*)((const float*)p + off);
}
__device__ __forceinline__ float lds1(const void* p, size_t off, bool isbf) {
    return isbf ? b2f(((const u16*)p)[off]) : ((const float*)p)[off];
}
// async 16B global -> LDS (dest = wave-uniform base + lane*16)
__device__ __forceinline__ void gll16(const void* g, void* l) {
    __builtin_amdgcn_global_load_lds(
        (const __attribute__((address_space(1))) u32*)g,
        (__attribute__((address_space(3))) u32*)l, 16, 0, 0);
}
// softcap + sliding-window mask. SCALING = 1/16, SOFTCAP = 50.
// masked -> -1e30, expf(-1e30) underflows to exactly 0.
__device__ __forceinline__ float capmask(float sdot, int i, int j) {
    float v = sdot * (0.0625f / 50.0f);
    v = fminf(fmaxf(v, -10.0f), 10.0f);
    float e = __expf(2.0f * v);
    float c = 50.0f * (e - 1.0f) / (e + 1.0f);
    bool allowed = (j <= i) && (j > i - 512);
    return allowed ? c : -1e30f;
}

// ---------------------------------------------------------------------------
// K0: prep = conv_hidden (blocks 0..2559) + weight transposes (2560..4159).
//   Hb[8192][640] bf16; WT[1536][640]; WoT[640][1024]
// ---------------------------------------------------------------------------
__global__ __launch_bounds__(256) void prep(
    const void* __restrict__ hidden,
    const void* __restrict__ Wq, const void* __restrict__ Wk,
    const void* __restrict__ Wv, const void* __restrict__ Wo,
    const void* __restrict__ cosT,
    u16* __restrict__ Hb, u16* __restrict__ WT, u16* __restrict__ WoT)
{
    const bool isbf = detect_bf16(cosT);
    __shared__ float T[32][33];
    int id = blockIdx.x;
    if (id < 2560) {
        size_t base = ((size_t)id * 256 + threadIdx.x) * 8;
        if (isbf) {
            *(uint4*)(Hb + base) = *(const uint4*)((const u16*)hidden + base);
        } else {
            float4 a = ld4(hidden, base, false);
            float4 b = ld4(hidden, base + 4, false);
            uint4 o;
            o.x = (u32)f2b(a.x) | ((u32)f2b(a.y) << 16);
            o.y = (u32)f2b(a.z) | ((u32)f2b(a.w) << 16);
            o.z = (u32)f2b(b.x) | ((u32)f2b(b.y) << 16);
            o.w = (u32)f2b(b.z) | ((u32)f2b(b.w) << 16);
            *(uint4*)(Hb + base) = o;
        }
        return;
    }
    id -= 2560;
    const int tx = threadIdx.x & 31, ty = threadIdx.x >> 5;
    if (id < 960) {
        const int n0 = (id % 48) * 32, k0 = (id / 48) * 32;
        const void* src; int ldw, nof;
        if (n0 < 1024)      { src = Wq; ldw = 1024; nof = n0; }
        else if (n0 < 1280) { src = Wk; ldw = 256;  nof = n0 - 1024; }
        else                { src = Wv; ldw = 256;  nof = n0 - 1280; }
#pragma unroll
        for (int j = 0; j < 4; j++)
            T[ty + 8 * j][tx] = lds1(src, (size_t)(k0 + ty + 8 * j) * ldw + nof + tx, isbf);
        __syncthreads();
#pragma unroll
        for (int j = 0; j < 4; j++)
            WT[(size_t)(n0 + ty + 8 * j) * 640 + k0 + tx] = f2b(T[tx][ty + 8 * j]);
    } else {
        id -= 960;
        const int k0 = (id & 31) * 32, n0 = (id >> 5) * 32;
#pragma unroll
        for (int j = 0; j < 4; j++)
            T[ty + 8 * j][tx] = lds1(Wo, (size_t)(k0 + ty + 8 * j) * 640 + n0 + tx, isbf);
        __syncthreads();
#pragma unroll
        for (int j = 0; j < 4; j++)
            WoT[(size_t)(n0 + ty + 8 * j) * 1024 + k0 + tx] = f2b(T[tx][ty + 8 * j]);
    }
}

// ---------------------------------------------------------------------------
// K1: QKV GEMM. 128x128 tile, BK=32, 4 waves, 16x16x32 MFMA.
// 2-phase double-buffered gll16 staging: issue stage of tile t+1, compute
// tile t, ONE __syncthreads() per tile (verified round 3; raw s_barrier
// version raced -- round 2, absmax 3.1e-2).
// LDS: dbuf A0|B0|A1|B1 (32 KB) overlaid by epilogue Sc (33.8 KB).
// (R4-verified config; R5's XCD swizzle + V-transpose epilogue reverted for
// clean attribution -- R5 bundled 4 changes and regressed +13.6 us.)
// ---------------------------------------------------------------------------
__global__ __launch_bounds__(256) void qkv_gemm(
    const u16* __restrict__ Hb, const u16* __restrict__ WT,
    u16* __restrict__ Qb, u16* __restrict__ Kb, u16* __restrict__ Vtg)
{
    const int n0 = blockIdx.x * 128, m0 = blockIdx.y * 128;
    const int t = threadIdx.x, w = t >> 6, lane = t & 63;
    const int l15 = lane & 15, quad = lane >> 4;
    const int wm = (w & 1) * 64, wn = (w >> 1) * 64;

    __shared__ __align__(16) char smem[33792];   // A0@0 B0@8K A1@16K B1@24K | Sc overlay

    f32x4 acc[4][4];
#pragma unroll
    for (int i = 0; i < 4; i++)
#pragma unroll
        for (int j = 0; j < 4; j++) acc[i][j] = (f32x4)0.0f;

    // prologue: stage tile 0 into half 0
#pragma unroll
    for (int i = 0; i < 2; i++) {
        int ci = t + 256 * i, m = ci >> 2, c = ci & 3;
        gll16(Hb + (size_t)(m0 + m) * 640 + c * 8, smem + ci * 16);
        gll16(WT + (size_t)(n0 + m) * 640 + c * 8, smem + 8192 + ci * 16);
    }
    __syncthreads();

    for (int it = 0; it < 20; ++it) {
        const int kb = it * 32;
        char* cur = smem + (it & 1) * 16384;
        if (it < 19) {
            char* nxt = smem + ((it + 1) & 1) * 16384;
#pragma unroll
            for (int i = 0; i < 2; i++) {
                int ci = t + 256 * i, m = ci >> 2, c = ci & 3;
                gll16(Hb + (size_t)(m0 + m) * 640 + kb + 32 + c * 8, nxt + ci * 16);
                gll16(WT + (size_t)(n0 + m) * 640 + kb + 32 + c * 8, nxt + 8192 + ci * 16);
            }
        }
        const u16 (*Ah)[32] = (const u16 (*)[32])cur;
        const u16 (*Bh)[32] = (const u16 (*)[32])(cur + 8192);
        bf16x8 af[4], bfr[4];
#pragma unroll
        for (int mi = 0; mi < 4; mi++)
            af[mi] = *(const bf16x8*)&Ah[wm + mi * 16 + l15][quad * 8];
#pragma unroll
        for (int ni = 0; ni < 4; ni++)
            bfr[ni] = *(const bf16x8*)&Bh[wn + ni * 16 + l15][quad * 8];
#pragma unroll
        for (int mi = 0; mi < 4; mi++)
#pragma unroll
            for (int ni = 0; ni < 4; ni++)
                acc[mi][ni] = __builtin_amdgcn_mfma_f32_16x16x32_bf16(
                    af[mi], bfr[ni], acc[mi][ni], 0, 0, 0);
        __syncthreads();
    }

    if (n0 >= 1280) {
        // V region: direct transposed store
        const int bb = m0 >> 12, sblk = m0 & 4095;
#pragma unroll
        for (int mi = 0; mi < 4; mi++)
#pragma unroll
            for (int ni = 0; ni < 4; ni++) {
                int vd = n0 + wn + ni * 16 + l15 - 1280;
                int sb = sblk + wm + mi * 16 + quad * 4;
                ushort4 vv = make_ushort4(f2b(acc[mi][ni][0]), f2b(acc[mi][ni][1]),
                                          f2b(acc[mi][ni][2]), f2b(acc[mi][ni][3]));
                *(ushort4*)(Vtg + (size_t)bb * 1048576 + (size_t)vd * 4096 + sb) = vv;
            }
        return;
    }

    // epilogue: staging buffers dead; overlay Sc for coalesced stores
    u16 (*Sc)[132] = (u16 (*)[132])smem;
#pragma unroll
    for (int mi = 0; mi < 4; mi++)
#pragma unroll
        for (int ni = 0; ni < 4; ni++)
#pragma unroll
            for (int r = 0; r < 4; r++)
                Sc[wm + mi * 16 + quad * 4 + r][wn + ni * 16 + l15] = f2b(acc[mi][ni][r]);
    __syncthreads();

    u16* dst; int ldo, coff;
    if (n0 < 1024) { dst = Qb; ldo = 1024; coff = n0; }
    else           { dst = Kb; ldo = 256;  coff = n0 - 1024; }
#pragma unroll
    for (int i = 0; i < 8; i++) {
        int idx = t + 256 * i, r = idx >> 4, c = idx & 15;
        *(uint4*)(dst + (size_t)(m0 + r) * ldo + coff + c * 8) = *(const uint4*)&Sc[r][c * 8];
    }
}

// ---------------------------------------------------------------------------
// K2: fused RMS-norm + RoPE in place on Qb (4 heads) and Kb (1 head).
// (R4-verified; the Q-fusion-into-attn experiment of R5 regressed attn
// 80->88.6 us for only ~9 us of norm savings -- reverted.)
// ---------------------------------------------------------------------------
__global__ __launch_bounds__(320) void norm_rope(
    u16* __restrict__ Qb, u16* __restrict__ Kb,
    const void* __restrict__ cosT, const void* __restrict__ sinT,
    const void* __restrict__ qw, const void* __restrict__ kw)
{
    const bool isbf = detect_bf16(cosT);
    const int row = blockIdx.x, s = row & 4095;
    const int g = threadIdx.x >> 6, lane = threadIdx.x & 63, d0 = lane * 4;

    u16* p; const void* w;
    if (g < 4) { p = Qb + (size_t)row * 1024 + g * 256 + d0; w = qw; }
    else       { p = Kb + (size_t)row * 256 + d0;            w = kw; }

    ushort4 xv = *(const ushort4*)p;
    float x0 = b2f(xv.x), x1 = b2f(xv.y), x2 = b2f(xv.z), x3 = b2f(xv.w);
    float ssum = x0 * x0 + x1 * x1 + x2 * x2 + x3 * x3;
#pragma unroll
    for (int off = 32; off > 0; off >>= 1) ssum += __shfl_xor(ssum, off, 64);
    float rs = rsqrtf(ssum * (1.0f / 256.0f) + 1e-6f);

    float4 wv = ld4(w, d0, isbf);
    float n0 = x0 * rs * (1.0f + wv.x);
    float n1 = x1 * rs * (1.0f + wv.y);
    float n2 = x2 * rs * (1.0f + wv.z);
    float n3 = x3 * rs * (1.0f + wv.w);

    float o0 = __shfl_xor(n0, 32, 64);
    float o1 = __shfl_xor(n1, 32, 64);
    float o2 = __shfl_xor(n2, 32, 64);
    float o3 = __shfl_xor(n3, 32, 64);
    float sgn = (lane < 32) ? -1.0f : 1.0f;

    float4 cv = ld4(cosT, (size_t)s * 256 + d0, isbf);
    float4 sv = ld4(sinT, (size_t)s * 256 + d0, isbf);
    *(ushort4*)p = make_ushort4(
        f2b(n0 * cv.x + sgn * o0 * sv.x), f2b(n1 * cv.y + sgn * o1 * sv.y),
        f2b(n2 * cv.z + sgn * o2 * sv.z), f2b(n3 * cv.w + sgn * o3 * sv.w));
}

// ---------------------------------------------------------------------------
// K3: sliding-window flash attention, 16x16x32 MFMA, KVBLK=64.
// Block = 8 waves = 4 heads x 2 q-halves = 32 queries; K/V staged per
// 64-key tile for all 32 queries.
// NEW (T2): Ks/Vt are XOR-swizzled, unpadded. R5 counters measured
// SQ_LDS_BANK_CONFLICT = 4.56M (~7.4 us/CU): the QK read (16 l15-lanes read
// 16 different K-rows at the same column) was a same-bank serialization.
// byte ^= ((row&7)<<4) spreads the 16-row column-slice over all 32 banks
// (2 lanes/bank = free). Swizzle applied on BOTH write and read sides
// (staging is plain ds_write_b128, so both-sides is legal -- rule #21).
// Pure layout change: numerics bit-identical.
// LDS: Ks 32K + Vt 32K + Pr 18.4K + l_s = ~83 KB, 1 block/CU (grid 256).
// XCD swizzle: q-tile = (bx&7)*16 + (bx>>3) -> per-XCD contiguous 512-query
// span, K/V ~2 MB in per-XCD L2. Fixed-max softmax (softcap bounds |s|<=50).
// P -> per-wave LDS -> B-operand of O^T = V^T P^T.
// 16x16 C/D: col=lane&15, row=(lane>>4)*4+reg.
// ---------------------------------------------------------------------------
__global__ __launch_bounds__(512, 2) void attn_mfma(
    const u16* __restrict__ Qb, const u16* __restrict__ Kb,
    const u16* __restrict__ Vtg, u16* __restrict__ AO)
{
    const int bx = blockIdx.x;                    // 0..127
    const int q0 = (((bx & 7) << 4) + (bx >> 3)) * 32;
    const int b  = blockIdx.y;
    const int t = threadIdx.x, w = t >> 6, lane = t & 63;
    const int h = w & 3, qh = w >> 2;
    const int l15 = lane & 15, quad = lane >> 4;
    const int qbase = q0 + qh * 16;
    const int swz = (l15 & 7) << 4;              // read-side XOR (row&7 == l15&7)

    __shared__ __align__(16) u16 Ks[64][256];    // 32 KB, XOR-swizzled rows (512B)
    __shared__ __align__(16) u16 Vt[256][64];    // 32 KB, XOR-swizzled rows (128B)
    __shared__ __align__(16) u16 Pr[8][16][72];
    __shared__ float l_s[8][16];

    // Q A-fragments: lane: q = qbase+l15, d = quad*8 + s*32 + j
    bf16x8 qf[8];
    {
        const u16* qp = Qb + ((size_t)(b * 4096 + qbase + l15)) * 1024 + h * 256 + quad * 8;
#pragma unroll
        for (int s = 0; s < 8; s++) qf[s] = *(const bf16x8*)(qp + s * 32);
    }

    f32x4 o[16];
#pragma unroll
    for (int i = 0; i < 16; i++) o[i] = (f32x4)0.0f;
    float lp[4] = {0.f, 0.f, 0.f, 0.f};

    const int lo = q0 - 511;
    const int jb0 = lo > 0 ? (lo >> 6) << 6 : 0;
    const int jb1 = (q0 + 31) & ~63;

    const u16* kbase = Kb + (size_t)b * 4096 * 256;
    const u16* vbase = Vtg + (size_t)b * 1048576;
    char* const ksb = (char*)&Ks[0][0];
    char* const vtb = (char*)&Vt[0][0];

    for (int jb = jb0; jb <= jb1; jb += 64) {
        __syncthreads();
        // stage K [64 keys][256 d] and Vt [256 d][64 keys], swizzled writes
#pragma unroll
        for (int i = 0; i < 4; i++) {
            int ci = t + 512 * i;
            int kr = ci >> 5, kc = ci & 31;
            *(uint4*)(ksb + kr * 512 + ((kc * 16) ^ ((kr & 7) << 4))) =
                *(const uint4*)(kbase + (size_t)(jb + kr) * 256 + kc * 8);
            int vr = ci >> 3, vc = ci & 7;
            *(uint4*)(vtb + vr * 128 + ((vc * 16) ^ ((vr & 7) << 4))) =
                *(const uint4*)(vbase + (size_t)vr * 4096 + jb + vc * 8);
        }
        __syncthreads();

        // ---- S = Q K^T : 16 queries x 64 keys (4 accs of 16x16)
        f32x4 s[4];
#pragma unroll
        for (int a = 0; a < 4; a++) s[a] = (f32x4)0.0f;
#pragma unroll
        for (int ds = 0; ds < 8; ds++) {
#pragma unroll
            for (int a = 0; a < 4; a++) {
                bf16x8 kf = *(const bf16x8*)(ksb + (a * 16 + l15) * 512 +
                                             (((ds * 4 + quad) * 16) ^ swz));
                s[a] = __builtin_amdgcn_mfma_f32_16x16x32_bf16(qf[ds], kf, s[a], 0, 0, 0);
            }
        }
        // ---- softcap + mask + exp (fixed max), P -> LDS
        // accumulate lp in pairs (a=0,1 then a=2,3) = same fp order as 32-key tiles
#pragma unroll
        for (int ap = 0; ap < 2; ap++) {
            const int j0 = jb + ap * 32 + l15;
#pragma unroll
            for (int r = 0; r < 4; r++) {
                int qi = qbase + quad * 4 + r;
                float p0 = __expf(capmask(s[2 * ap][r],     qi, j0));
                float p1 = __expf(capmask(s[2 * ap + 1][r], qi, j0 + 16));
                u16 pb0 = f2b(p0), pb1 = f2b(p1);
                Pr[w][quad * 4 + r][ap * 32 + l15]      = pb0;
                Pr[w][quad * 4 + r][ap * 32 + 16 + l15] = pb1;
                lp[r] += b2f(pb0) + b2f(pb1);
            }
        }
        __threadfence_block();
        // ---- O^T += V^T P^T (two 32-k slices, same order as two old tiles)
        bf16x8 pf0 = *(const bf16x8*)&Pr[w][l15][quad * 8];
        bf16x8 pf1 = *(const bf16x8*)&Pr[w][l15][32 + quad * 8];
#pragma unroll
        for (int mt = 0; mt < 16; mt++) {
            bf16x8 vf0 = *(const bf16x8*)(vtb + (mt * 16 + l15) * 128 +
                                          ((quad * 16) ^ swz));
            o[mt] = __builtin_amdgcn_mfma_f32_16x16x32_bf16(vf0, pf0, o[mt], 0, 0, 0);
        }
#pragma unroll
        for (int mt = 0; mt < 16; mt++) {
            bf16x8 vf1 = *(const bf16x8*)(vtb + (mt * 16 + l15) * 128 +
                                          (((4 + quad) * 16) ^ swz));
            o[mt] = __builtin_amdgcn_mfma_f32_16x16x32_bf16(vf1, pf1, o[mt], 0, 0, 0);
        }
    }

    // ---- l reduction across the 16 key-lanes
#pragma unroll
    for (int r = 0; r < 4; r++) {
        float v = lp[r];
        v += __shfl_xor(v, 1, 64); v += __shfl_xor(v, 2, 64);
        v += __shfl_xor(v, 4, 64); v += __shfl_xor(v, 8, 64);
        lp[r] = v;
    }
    if (l15 == 0) {
#pragma unroll
        for (int r = 0; r < 4; r++) l_s[w][quad * 4 + r] = lp[r];
    }
    __threadfence_block();
    __syncthreads();
    const float inv = 1.0f / l_s[w][l15];

    u16* aop = AO + ((size_t)(b * 4096 + qbase + l15)) * 1024 + h * 256 + quad * 4;
#pragma unroll
    for (int mt = 0; mt < 16; mt++) {
        *(ushort4*)(aop + mt * 16) = make_ushort4(
            f2b(o[mt][0] * inv), f2b(o[mt][1] * inv),
            f2b(o[mt][2] * inv), f2b(o[mt][3] * inv));
    }
}

// ---------------------------------------------------------------------------
// K4: output projection. BM=128, BN=64 -> grid (10,64). 4 waves 2x2 of 64x32.
// 2-phase dbuf staging (one __syncthreads per tile); dbuf 24 KB overlaid by
// Scf (34.8 KB). (R4-verified config; R5 XCD swizzle reverted.)
// ---------------------------------------------------------------------------
__global__ __launch_bounds__(256) void out_gemm(
    const u16* __restrict__ AO, const u16* __restrict__ WoT,
    const void* __restrict__ cosT, void* __restrict__ outp)
{
    const bool isbf = detect_bf16(cosT);
    const int n0 = blockIdx.x * 64, m0 = blockIdx.y * 128;
    const int t = threadIdx.x, w = t >> 6, lane = t & 63;
    const int l15 = lane & 15, quad = lane >> 4;
    const int wm = (w & 1) * 64, wn = (w >> 1) * 32;

    __shared__ __align__(16) char smem[34816];   // A0@0 B0@8K A1@12K B1@20K | Scf overlay

    f32x4 acc[4][2];
#pragma unroll
    for (int i = 0; i < 4; i++)
#pragma unroll
        for (int j = 0; j < 2; j++) acc[i][j] = (f32x4)0.0f;

    // prologue: stage tile 0 into half 0
    {
#pragma unroll
        for (int i = 0; i < 2; i++) {
            int ci = t + 256 * i, m = ci >> 2, c = ci & 3;
            gll16(AO + (size_t)(m0 + m) * 1024 + c * 8, smem + ci * 16);
        }
        int m = t >> 2, c = t & 3;
        gll16(WoT + (size_t)(n0 + m) * 1024 + c * 8, smem + 8192 + t * 16);
    }
    __syncthreads();

    for (int it = 0; it < 32; ++it) {
        const int kb = it * 32;
        char* cur = smem + (it & 1) * 12288;
        if (it < 31) {
            char* nxt = smem + ((it + 1) & 1) * 12288;
#pragma unroll
            for (int i = 0; i < 2; i++) {
                int ci = t + 256 * i, m = ci >> 2, c = ci & 3;
                gll16(AO + (size_t)(m0 + m) * 1024 + kb + 32 + c * 8, nxt + ci * 16);
            }
            int m = t >> 2, c = t & 3;
            gll16(WoT + (size_t)(n0 + m) * 1024 + kb + 32 + c * 8, nxt + 8192 + t * 16);
        }
        const u16 (*Ah)[32] = (const u16 (*)[32])cur;
        const u16 (*Bh)[32] = (const u16 (*)[32])(cur + 8192);
        bf16x8 af[4], bfr[2];
#pragma unroll
        for (int mi = 0; mi < 4; mi++)
            af[mi] = *(const bf16x8*)&Ah[wm + mi * 16 + l15][quad * 8];
#pragma unroll
        for (int ni = 0; ni < 2; ni++)
            bfr[ni] = *(const bf16x8*)&Bh[wn + ni * 16 + l15][quad * 8];
#pragma unroll
        for (int mi = 0; mi < 4; mi++)
#pragma unroll
            for (int ni = 0; ni < 2; ni++)
                acc[mi][ni] = __builtin_amdgcn_mfma_f32_16x16x32_bf16(
                    af[mi], bfr[ni], acc[mi][ni], 0, 0, 0);
        __syncthreads();
    }

    float (*Scf)[68] = (float (*)[68])smem;
#pragma unroll
    for (int mi = 0; mi < 4; mi++)
#pragma unroll
        for (int ni = 0; ni < 2; ni++)
#pragma unroll
            for (int r = 0; r < 4; r++)
                Scf[wm + mi * 16 + quad * 4 + r][wn + ni * 16 + l15] = acc[mi][ni][r];
    __syncthreads();

    if (isbf) {
#pragma unroll
        for (int i = 0; i < 4; i++) {
            int idx = t + 256 * i, r = idx >> 3, c = idx & 7;   // 128 rows x 8 chunks(8 cols)
            ushort4 lo4 = make_ushort4(
                f2b(Scf[r][c * 8 + 0]), f2b(Scf[r][c * 8 + 1]),
                f2b(Scf[r][c * 8 + 2]), f2b(Scf[r][c * 8 + 3]));
            ushort4 hi4 = make_ushort4(
                f2b(Scf[r][c * 8 + 4]), f2b(Scf[r][c * 8 + 5]),
                f2b(Scf[r][c * 8 + 6]), f2b(Scf[r][c * 8 + 7]));
            u16* p = (u16*)outp + (size_t)(m0 + r) * 640 + n0 + c * 8;
            *(ushort4*)p = lo4; *(ushort4*)(p + 4) = hi4;
        }
    } else {
#pragma unroll
        for (int i = 0; i < 8; i++) {
            int idx = t + 256 * i, r = idx >> 4, c = idx & 15;  // 128 rows x 16 chunks(4 cols)
            float4 v = *(const float4*)&Scf[r][c * 4];
            *(float4*)((float*)outp + (size_t)(m0 + r) * 640 + n0 + c * 4) = v;
        }
    }
}

// ---------------------------------------------------------------------------
// Launch. Inputs: 0 hidden, 1 cos, 2 sin, 3 mask(UNUSED), 4 Wq, 5 Wk, 6 Wv,
// 7 Wo, 8 q_norm_w, 9 k_norm_w. Workspace (43.3 MB, AO overlays Hb+WT):
//   [0, 16.78M): Hb(10.49M) + WT(1.97M)  -- dead after GEMMs; AO reuses @0
//   [16.78M): WoT 1.31M | Qb 16.78M | Kb 4.19M | Vt_g 4.19M
// ---------------------------------------------------------------------------
extern "C" void kernel_launch(void* const* d_in, const int* in_sizes, int n_in,
                              void* d_out, int out_size, void* d_ws, size_t ws_size,
                              hipStream_t stream) {
    const void* hidden = d_in[0];
    const void* cosT   = d_in[1];
    const void* sinT   = d_in[2];
    const void* Wq     = d_in[4];
    const void* Wk     = d_in[5];
    const void* Wv     = d_in[6];
    const void* Wo     = d_in[7];
    const void* qw     = d_in[8];
    const void* kw     = d_in[9];

    char* ws = (char*)d_ws;
    u16* Hb  = (u16*)ws;                            // 8192*640
    u16* WT  = (u16*)(ws + 10485760);               // 1536*640
    u16* AO  = (u16*)ws;                            // 8192*1024 (overlays Hb/WT)
    u16* WoT = (u16*)(ws + 16777216);               // 640*1024
    u16* Qb  = (u16*)(ws + 18087936);               // 8192*1024
    u16* Kb  = (u16*)(ws + 34865152);               // 8192*256
    u16* Vtg = (u16*)(ws + 39059456);               // 2*256*4096

    prep<<<dim3(4160), 256, 0, stream>>>(hidden, Wq, Wk, Wv, Wo, cosT, Hb, WT, WoT);
    qkv_gemm<<<dim3(12, 64), 256, 0, stream>>>(Hb, WT, Qb, Kb, Vtg);
    norm_rope<<<dim3(8192), 320, 0, stream>>>(Qb, Kb, cosT, sinT, qw, kw);
    attn_mfma<<<dim3(128, 2), 512, 0, stream>>>(Qb, Kb, Vtg, AO);
    out_gemm<<<dim3(10, 64), 256, 0, stream>>>(AO, WoT, cosT, d_out);
}

// Round 7
// 309.866 us; speedup vs baseline: 1.0471x; 1.0014x over previous
//
#include <hip/hip_runtime.h>

typedef unsigned short u16;
typedef unsigned int u32;

typedef __attribute__((ext_vector_type(8)))  short bf16x8;
typedef __attribute__((ext_vector_type(4)))  float f32x4;

__device__ __forceinline__ float b2f(u16 u) {
    union { unsigned int i; float f; } v; v.i = ((unsigned int)u) << 16; return v.f;
}
__device__ __forceinline__ u16 f2b(float f) {
    union { float ff; unsigned int i; } v; v.ff = f;
    unsigned int x = v.i;
    return (u16)((x + 0x7fffu + ((x >> 16) & 1u)) >> 16);
}
__device__ __forceinline__ bool detect_bf16(const void* cosT) {
    // cos row 0 is all 1.0: fp32 word = 0x3F800000, bf16 pair = 0x3F803F80
    return ((*(const u32*)cosT) & 0xffffu) == 0x3f80u;
}
__device__ __forceinline__ float4 ld4(const void* p, size_t off, bool isbf) {
    if (isbf) {
        ushort4 v = *(const ushort4*)((const u16*)p + off);
        return make_float4(b2f(v.x), b2f(v.y), b2f(v.z), b2f(v.w));
    }
    return *(const float4*)((const float*)p + off);
}
__device__ __forceinline__ float lds1(const void* p, size_t off, bool isbf) {
    return isbf ? b2f(((const u16*)p)[off]) : ((const float*)p)[off];
}
// async 16B global -> LDS (dest = wave-uniform base + lane*16)
__device__ __forceinline__ void gll16(const void* g, void* l) {
    __builtin_amdgcn_global_load_lds(
        (const __attribute__((address_space(1))) u32*)g,
        (__attribute__((address_space(3))) u32*)l, 16, 0, 0);
}
// softcap + sliding-window mask. SCALING = 1/16, SOFTCAP = 50.
// masked -> -1e30, expf(-1e30) underflows to exactly 0.
__device__ __forceinline__ float capmask(float sdot, int i, int j) {
    float v = sdot * (0.0625f / 50.0f);
    v = fminf(fmaxf(v, -10.0f), 10.0f);
    float e = __expf(2.0f * v);
    float c = 50.0f * (e - 1.0f) / (e + 1.0f);
    bool allowed = (j <= i) && (j > i - 512);
    return allowed ? c : -1e30f;
}

// ---------------------------------------------------------------------------
// K0: prep = conv_hidden (blocks 0..2559) + weight transposes (2560..4159).
//   Hb[8192][640] bf16; WT[1536][640]; WoT[640][1024]
// ---------------------------------------------------------------------------
__global__ __launch_bounds__(256) void prep(
    const void* __restrict__ hidden,
    const void* __restrict__ Wq, const void* __restrict__ Wk,
    const void* __restrict__ Wv, const void* __restrict__ Wo,
    const void* __restrict__ cosT,
    u16* __restrict__ Hb, u16* __restrict__ WT, u16* __restrict__ WoT)
{
    const bool isbf = detect_bf16(cosT);
    __shared__ float T[32][33];
    int id = blockIdx.x;
    if (id < 2560) {
        size_t base = ((size_t)id * 256 + threadIdx.x) * 8;
        if (isbf) {
            *(uint4*)(Hb + base) = *(const uint4*)((const u16*)hidden + base);
        } else {
            float4 a = ld4(hidden, base, false);
            float4 b = ld4(hidden, base + 4, false);
            uint4 o;
            o.x = (u32)f2b(a.x) | ((u32)f2b(a.y) << 16);
            o.y = (u32)f2b(a.z) | ((u32)f2b(a.w) << 16);
            o.z = (u32)f2b(b.x) | ((u32)f2b(b.y) << 16);
            o.w = (u32)f2b(b.z) | ((u32)f2b(b.w) << 16);
            *(uint4*)(Hb + base) = o;
        }
        return;
    }
    id -= 2560;
    const int tx = threadIdx.x & 31, ty = threadIdx.x >> 5;
    if (id < 960) {
        const int n0 = (id % 48) * 32, k0 = (id / 48) * 32;
        const void* src; int ldw, nof;
        if (n0 < 1024)      { src = Wq; ldw = 1024; nof = n0; }
        else if (n0 < 1280) { src = Wk; ldw = 256;  nof = n0 - 1024; }
        else                { src = Wv; ldw = 256;  nof = n0 - 1280; }
#pragma unroll
        for (int j = 0; j < 4; j++)
            T[ty + 8 * j][tx] = lds1(src, (size_t)(k0 + ty + 8 * j) * ldw + nof + tx, isbf);
        __syncthreads();
#pragma unroll
        for (int j = 0; j < 4; j++)
            WT[(size_t)(n0 + ty + 8 * j) * 640 + k0 + tx] = f2b(T[tx][ty + 8 * j]);
    } else {
        id -= 960;
        const int k0 = (id & 31) * 32, n0 = (id >> 5) * 32;
#pragma unroll
        for (int j = 0; j < 4; j++)
            T[ty + 8 * j][tx] = lds1(Wo, (size_t)(k0 + ty + 8 * j) * 640 + n0 + tx, isbf);
        __syncthreads();
#pragma unroll
        for (int j = 0; j < 4; j++)
            WoT[(size_t)(n0 + ty + 8 * j) * 1024 + k0 + tx] = f2b(T[tx][ty + 8 * j]);
    }
}

// ---------------------------------------------------------------------------
// K1: QKV GEMM. 128x128 tile, BK=32, 4 waves, 16x16x32 MFMA.
// 2-phase double-buffered gll16 staging: issue stage of tile t+1, compute
// tile t, ONE __syncthreads() per tile (verified round 3; raw s_barrier
// version raced -- round 2, absmax 3.1e-2).
// LDS: dbuf A0|B0|A1|B1 (32 KB) overlaid by epilogue Sc (33.8 KB).
// ---------------------------------------------------------------------------
__global__ __launch_bounds__(256) void qkv_gemm(
    const u16* __restrict__ Hb, const u16* __restrict__ WT,
    u16* __restrict__ Qb, u16* __restrict__ Kb, u16* __restrict__ Vtg)
{
    const int n0 = blockIdx.x * 128, m0 = blockIdx.y * 128;
    const int t = threadIdx.x, w = t >> 6, lane = t & 63;
    const int l15 = lane & 15, quad = lane >> 4;
    const int wm = (w & 1) * 64, wn = (w >> 1) * 64;

    __shared__ __align__(16) char smem[33792];   // A0@0 B0@8K A1@16K B1@24K | Sc overlay

    f32x4 acc[4][4];
#pragma unroll
    for (int i = 0; i < 4; i++)
#pragma unroll
        for (int j = 0; j < 4; j++) acc[i][j] = (f32x4)0.0f;

    // prologue: stage tile 0 into half 0
#pragma unroll
    for (int i = 0; i < 2; i++) {
        int ci = t + 256 * i, m = ci >> 2, c = ci & 3;
        gll16(Hb + (size_t)(m0 + m) * 640 + c * 8, smem + ci * 16);
        gll16(WT + (size_t)(n0 + m) * 640 + c * 8, smem + 8192 + ci * 16);
    }
    __syncthreads();

    for (int it = 0; it < 20; ++it) {
        const int kb = it * 32;
        char* cur = smem + (it & 1) * 16384;
        if (it < 19) {
            char* nxt = smem + ((it + 1) & 1) * 16384;
#pragma unroll
            for (int i = 0; i < 2; i++) {
                int ci = t + 256 * i, m = ci >> 2, c = ci & 3;
                gll16(Hb + (size_t)(m0 + m) * 640 + kb + 32 + c * 8, nxt + ci * 16);
                gll16(WT + (size_t)(n0 + m) * 640 + kb + 32 + c * 8, nxt + 8192 + ci * 16);
            }
        }
        const u16 (*Ah)[32] = (const u16 (*)[32])cur;
        const u16 (*Bh)[32] = (const u16 (*)[32])(cur + 8192);
        bf16x8 af[4], bfr[4];
#pragma unroll
        for (int mi = 0; mi < 4; mi++)
            af[mi] = *(const bf16x8*)&Ah[wm + mi * 16 + l15][quad * 8];
#pragma unroll
        for (int ni = 0; ni < 4; ni++)
            bfr[ni] = *(const bf16x8*)&Bh[wn + ni * 16 + l15][quad * 8];
#pragma unroll
        for (int mi = 0; mi < 4; mi++)
#pragma unroll
            for (int ni = 0; ni < 4; ni++)
                acc[mi][ni] = __builtin_amdgcn_mfma_f32_16x16x32_bf16(
                    af[mi], bfr[ni], acc[mi][ni], 0, 0, 0);
        __syncthreads();
    }

    if (n0 >= 1280) {
        // V region: direct transposed store
        const int bb = m0 >> 12, sblk = m0 & 4095;
#pragma unroll
        for (int mi = 0; mi < 4; mi++)
#pragma unroll
            for (int ni = 0; ni < 4; ni++) {
                int vd = n0 + wn + ni * 16 + l15 - 1280;
                int sb = sblk + wm + mi * 16 + quad * 4;
                ushort4 vv = make_ushort4(f2b(acc[mi][ni][0]), f2b(acc[mi][ni][1]),
                                          f2b(acc[mi][ni][2]), f2b(acc[mi][ni][3]));
                *(ushort4*)(Vtg + (size_t)bb * 1048576 + (size_t)vd * 4096 + sb) = vv;
            }
        return;
    }

    // epilogue: staging buffers dead; overlay Sc for coalesced stores
    u16 (*Sc)[132] = (u16 (*)[132])smem;
#pragma unroll
    for (int mi = 0; mi < 4; mi++)
#pragma unroll
        for (int ni = 0; ni < 4; ni++)
#pragma unroll
            for (int r = 0; r < 4; r++)
                Sc[wm + mi * 16 + quad * 4 + r][wn + ni * 16 + l15] = f2b(acc[mi][ni][r]);
    __syncthreads();

    u16* dst; int ldo, coff;
    if (n0 < 1024) { dst = Qb; ldo = 1024; coff = n0; }
    else           { dst = Kb; ldo = 256;  coff = n0 - 1024; }
#pragma unroll
    for (int i = 0; i < 8; i++) {
        int idx = t + 256 * i, r = idx >> 4, c = idx & 15;
        *(uint4*)(dst + (size_t)(m0 + r) * ldo + coff + c * 8) = *(const uint4*)&Sc[r][c * 8];
    }
}

// ---------------------------------------------------------------------------
// K2: fused RMS-norm + RoPE in place on Qb (4 heads) and Kb (1 head).
// ---------------------------------------------------------------------------
__global__ __launch_bounds__(320) void norm_rope(
    u16* __restrict__ Qb, u16* __restrict__ Kb,
    const void* __restrict__ cosT, const void* __restrict__ sinT,
    const void* __restrict__ qw, const void* __restrict__ kw)
{
    const bool isbf = detect_bf16(cosT);
    const int row = blockIdx.x, s = row & 4095;
    const int g = threadIdx.x >> 6, lane = threadIdx.x & 63, d0 = lane * 4;

    u16* p; const void* w;
    if (g < 4) { p = Qb + (size_t)row * 1024 + g * 256 + d0; w = qw; }
    else       { p = Kb + (size_t)row * 256 + d0;            w = kw; }

    ushort4 xv = *(const ushort4*)p;
    float x0 = b2f(xv.x), x1 = b2f(xv.y), x2 = b2f(xv.z), x3 = b2f(xv.w);
    float ssum = x0 * x0 + x1 * x1 + x2 * x2 + x3 * x3;
#pragma unroll
    for (int off = 32; off > 0; off >>= 1) ssum += __shfl_xor(ssum, off, 64);
    float rs = rsqrtf(ssum * (1.0f / 256.0f) + 1e-6f);

    float4 wv = ld4(w, d0, isbf);
    float n0 = x0 * rs * (1.0f + wv.x);
    float n1 = x1 * rs * (1.0f + wv.y);
    float n2 = x2 * rs * (1.0f + wv.z);
    float n3 = x3 * rs * (1.0f + wv.w);

    float o0 = __shfl_xor(n0, 32, 64);
    float o1 = __shfl_xor(n1, 32, 64);
    float o2 = __shfl_xor(n2, 32, 64);
    float o3 = __shfl_xor(n3, 32, 64);
    float sgn = (lane < 32) ? -1.0f : 1.0f;

    float4 cv = ld4(cosT, (size_t)s * 256 + d0, isbf);
    float4 sv = ld4(sinT, (size_t)s * 256 + d0, isbf);
    *(ushort4*)p = make_ushort4(
        f2b(n0 * cv.x + sgn * o0 * sv.x), f2b(n1 * cv.y + sgn * o1 * sv.y),
        f2b(n2 * cv.z + sgn * o2 * sv.z), f2b(n3 * cv.w + sgn * o3 * sv.w));
}

// ---------------------------------------------------------------------------
// K3: sliding-window flash attention, 16x16x32 MFMA, KVBLK=64.
// Block = 8 waves = 4 heads x 2 q-halves = 32 queries.
// NEW (T3+T4): double-buffered K/V staging via global_load_lds with COUNTED
// vmcnt. R5/R6 showed staging (64KB L2->LDS per tile, ~1200cy) was serialized
// against compute between barriers. Now: issue 8 gll16/thread for tile t+1,
// s_waitcnt vmcnt(8) (drains only tile t's loads), barrier, compute tile t.
// Loads for t+1 stay in flight across the barrier under the compute phase.
// Race discipline (rule 18 / R2 lesson): memory-clobber asm BEFORE each
// s_barrier; sched_barrier(0) AFTER each; 2 barriers/tile (end barrier
// protects the buffer the NEXT iteration overwrites -- depth-2 reuse).
// Swizzle kept via PRE-SWIZZLED GLOBAL SOURCE (rule 21: gll16 dest linear,
// source chunk = c ^ (row&7), read applies same XOR -- involution).
// LDS: 2x(32K Ks + 32K Vt) + Pr 18.4K + l_s = 146.5 KB; 1 block/CU (grid 256).
// XCD swizzle: q-tile = (bx&7)*16 + (bx>>3). Fixed-max softmax.
// P -> per-wave LDS -> B-operand of O^T = V^T P^T.
// ---------------------------------------------------------------------------
__global__ __launch_bounds__(512, 2) void attn_mfma(
    const u16* __restrict__ Qb, const u16* __restrict__ Kb,
    const u16* __restrict__ Vtg, u16* __restrict__ AO)
{
    const int bx = blockIdx.x;                    // 0..127
    const int q0 = (((bx & 7) << 4) + (bx >> 3)) * 32;
    const int b  = blockIdx.y;
    const int t = threadIdx.x, w = t >> 6, lane = t & 63;
    const int h = w & 3, qh = w >> 2;
    const int l15 = lane & 15, quad = lane >> 4;
    const int qbase = q0 + qh * 16;
    const int swz = (l15 & 7) << 4;              // read-side XOR (row&7 == l15&7)

    __shared__ __align__(16) u16 KsD[2][64][256];   // 64 KB, XOR-swizzled rows (512B)
    __shared__ __align__(16) u16 VtD[2][256][64];   // 64 KB, XOR-swizzled rows (128B)
    __shared__ __align__(16) u16 Pr[8][16][72];
    __shared__ float l_s[8][16];

    // Q A-fragments: lane: q = qbase+l15, d = quad*8 + s*32 + j
    bf16x8 qf[8];
    {
        const u16* qp = Qb + ((size_t)(b * 4096 + qbase + l15)) * 1024 + h * 256 + quad * 8;
#pragma unroll
        for (int s = 0; s < 8; s++) qf[s] = *(const bf16x8*)(qp + s * 32);
    }

    f32x4 o[16];
#pragma unroll
    for (int i = 0; i < 16; i++) o[i] = (f32x4)0.0f;
    float lp[4] = {0.f, 0.f, 0.f, 0.f};

    const int lo = q0 - 511;
    const int jb0 = lo > 0 ? (lo >> 6) << 6 : 0;
    const int jb1 = (q0 + 31) & ~63;
    const int nt  = ((jb1 - jb0) >> 6) + 1;

    const u16* kbase = Kb + (size_t)b * 4096 * 256;
    const u16* vbase = Vtg + (size_t)b * 1048576;

    // stage tile at jb into buffer bi: linear gll16 dest, source pre-swizzled
#define STAGE_KV(jb_, bi_)                                                          \
    {                                                                               \
        char* kd = (char*)&KsD[bi_][0][0];                                          \
        char* vd = (char*)&VtD[bi_][0][0];                                          \
        _Pragma("unroll")                                                           \
        for (int i_ = 0; i_ < 4; i_++) {                                            \
            int ci = t + 512 * i_;                                                  \
            int kr = ci >> 5, kc = ci & 31;                                         \
            gll16(kbase + (size_t)((jb_) + kr) * 256 + ((kc ^ (kr & 7)) * 8),       \
                  kd + ci * 16);                                                    \
            int vr = ci >> 3, vc = ci & 7;                                          \
            gll16(vbase + (size_t)vr * 4096 + (jb_) + ((vc ^ (vr & 7)) * 8),        \
                  vd + ci * 16);                                                    \
        }                                                                           \
    }

    STAGE_KV(jb0, 0);

    for (int it = 0; it < nt; ++it) {
        const int jb = jb0 + it * 64;
        if (it + 1 < nt) {
            STAGE_KV(jb + 64, (it + 1) & 1);
            asm volatile("s_waitcnt vmcnt(8)" ::: "memory");   // tile it's 8 done
        } else {
            asm volatile("s_waitcnt vmcnt(0)" ::: "memory");
        }
        __builtin_amdgcn_s_barrier();
        __builtin_amdgcn_sched_barrier(0);

        const char* ksb = (const char*)&KsD[it & 1][0][0];
        const char* vtb = (const char*)&VtD[it & 1][0][0];

        // ---- S = Q K^T : 16 queries x 64 keys (4 accs of 16x16)
        f32x4 s[4];
#pragma unroll
        for (int a = 0; a < 4; a++) s[a] = (f32x4)0.0f;
#pragma unroll
        for (int ds = 0; ds < 8; ds++) {
#pragma unroll
            for (int a = 0; a < 4; a++) {
                bf16x8 kf = *(const bf16x8*)(ksb + (a * 16 + l15) * 512 +
                                             (((ds * 4 + quad) * 16) ^ swz));
                s[a] = __builtin_amdgcn_mfma_f32_16x16x32_bf16(qf[ds], kf, s[a], 0, 0, 0);
            }
        }
        // ---- softcap + mask + exp (fixed max), P -> LDS
        // accumulate lp in pairs (a=0,1 then a=2,3) = same fp order as 32-key tiles
#pragma unroll
        for (int ap = 0; ap < 2; ap++) {
            const int j0 = jb + ap * 32 + l15;
#pragma unroll
            for (int r = 0; r < 4; r++) {
                int qi = qbase + quad * 4 + r;
                float p0 = __expf(capmask(s[2 * ap][r],     qi, j0));
                float p1 = __expf(capmask(s[2 * ap + 1][r], qi, j0 + 16));
                u16 pb0 = f2b(p0), pb1 = f2b(p1);
                Pr[w][quad * 4 + r][ap * 32 + l15]      = pb0;
                Pr[w][quad * 4 + r][ap * 32 + 16 + l15] = pb1;
                lp[r] += b2f(pb0) + b2f(pb1);
            }
        }
        __threadfence_block();
        // ---- O^T += V^T P^T (two 32-k slices, same order as two old tiles)
        bf16x8 pf0 = *(const bf16x8*)&Pr[w][l15][quad * 8];
        bf16x8 pf1 = *(const bf16x8*)&Pr[w][l15][32 + quad * 8];
#pragma unroll
        for (int mt = 0; mt < 16; mt++) {
            bf16x8 vf0 = *(const bf16x8*)(vtb + (mt * 16 + l15) * 128 +
                                          ((quad * 16) ^ swz));
            o[mt] = __builtin_amdgcn_mfma_f32_16x16x32_bf16(vf0, pf0, o[mt], 0, 0, 0);
        }
#pragma unroll
        for (int mt = 0; mt < 16; mt++) {
            bf16x8 vf1 = *(const bf16x8*)(vtb + (mt * 16 + l15) * 128 +
                                          (((4 + quad) * 16) ^ swz));
            o[mt] = __builtin_amdgcn_mfma_f32_16x16x32_bf16(vf1, pf1, o[mt], 0, 0, 0);
        }

        // end barrier: all waves done reading buf[it&1] before iteration it+1
        // stages into buf[(it+2)&1] == buf[it&1].
        asm volatile("s_waitcnt lgkmcnt(0)" ::: "memory");
        __builtin_amdgcn_s_barrier();
        __builtin_amdgcn_sched_barrier(0);
    }
#undef STAGE_KV

    // ---- l reduction across the 16 key-lanes
#pragma unroll
    for (int r = 0; r < 4; r++) {
        float v = lp[r];
        v += __shfl_xor(v, 1, 64); v += __shfl_xor(v, 2, 64);
        v += __shfl_xor(v, 4, 64); v += __shfl_xor(v, 8, 64);
        lp[r] = v;
    }
    if (l15 == 0) {
#pragma unroll
        for (int r = 0; r < 4; r++) l_s[w][quad * 4 + r] = lp[r];
    }
    __threadfence_block();
    __syncthreads();
    const float inv = 1.0f / l_s[w][l15];

    u16* aop = AO + ((size_t)(b * 4096 + qbase + l15)) * 1024 + h * 256 + quad * 4;
#pragma unroll
    for (int mt = 0; mt < 16; mt++) {
        *(ushort4*)(aop + mt * 16) = make_ushort4(
            f2b(o[mt][0] * inv), f2b(o[mt][1] * inv),
            f2b(o[mt][2] * inv), f2b(o[mt][3] * inv));
    }
}

// ---------------------------------------------------------------------------
// K4: output projection. BM=128, BN=64 -> grid (10,64). 4 waves 2x2 of 64x32.
// 2-phase dbuf staging (one __syncthreads per tile); dbuf 24 KB overlaid by
// Scf (34.8 KB).
// ---------------------------------------------------------------------------
__global__ __launch_bounds__(256) void out_gemm(
    const u16* __restrict__ AO, const u16* __restrict__ WoT,
    const void* __restrict__ cosT, void* __restrict__ outp)
{
    const bool isbf = detect_bf16(cosT);
    const int n0 = blockIdx.x * 64, m0 = blockIdx.y * 128;
    const int t = threadIdx.x, w = t >> 6, lane = t & 63;
    const int l15 = lane & 15, quad = lane >> 4;
    const int wm = (w & 1) * 64, wn = (w >> 1) * 32;

    __shared__ __align__(16) char smem[34816];   // A0@0 B0@8K A1@12K B1@20K | Scf overlay

    f32x4 acc[4][2];
#pragma unroll
    for (int i = 0; i < 4; i++)
#pragma unroll
        for (int j = 0; j < 2; j++) acc[i][j] = (f32x4)0.0f;

    // prologue: stage tile 0 into half 0
    {
#pragma unroll
        for (int i = 0; i < 2; i++) {
            int ci = t + 256 * i, m = ci >> 2, c = ci & 3;
            gll16(AO + (size_t)(m0 + m) * 1024 + c * 8, smem + ci * 16);
        }
        int m = t >> 2, c = t & 3;
        gll16(WoT + (size_t)(n0 + m) * 1024 + c * 8, smem + 8192 + t * 16);
    }
    __syncthreads();

    for (int it = 0; it < 32; ++it) {
        const int kb = it * 32;
        char* cur = smem + (it & 1) * 12288;
        if (it < 31) {
            char* nxt = smem + ((it + 1) & 1) * 12288;
#pragma unroll
            for (int i = 0; i < 2; i++) {
                int ci = t + 256 * i, m = ci >> 2, c = ci & 3;
                gll16(AO + (size_t)(m0 + m) * 1024 + kb + 32 + c * 8, nxt + ci * 16);
            }
            int m = t >> 2, c = t & 3;
            gll16(WoT + (size_t)(n0 + m) * 1024 + kb + 32 + c * 8, nxt + 8192 + t * 16);
        }
        const u16 (*Ah)[32] = (const u16 (*)[32])cur;
        const u16 (*Bh)[32] = (const u16 (*)[32])(cur + 8192);
        bf16x8 af[4], bfr[2];
#pragma unroll
        for (int mi = 0; mi < 4; mi++)
            af[mi] = *(const bf16x8*)&Ah[wm + mi * 16 + l15][quad * 8];
#pragma unroll
        for (int ni = 0; ni < 2; ni++)
            bfr[ni] = *(const bf16x8*)&Bh[wn + ni * 16 + l15][quad * 8];
#pragma unroll
        for (int mi = 0; mi < 4; mi++)
#pragma unroll
            for (int ni = 0; ni < 2; ni++)
                acc[mi][ni] = __builtin_amdgcn_mfma_f32_16x16x32_bf16(
                    af[mi], bfr[ni], acc[mi][ni], 0, 0, 0);
        __syncthreads();
    }

    float (*Scf)[68] = (float (*)[68])smem;
#pragma unroll
    for (int mi = 0; mi < 4; mi++)
#pragma unroll
        for (int ni = 0; ni < 2; ni++)
#pragma unroll
            for (int r = 0; r < 4; r++)
                Scf[wm + mi * 16 + quad * 4 + r][wn + ni * 16 + l15] = acc[mi][ni][r];
    __syncthreads();

    if (isbf) {
#pragma unroll
        for (int i = 0; i < 4; i++) {
            int idx = t + 256 * i, r = idx >> 3, c = idx & 7;   // 128 rows x 8 chunks(8 cols)
            ushort4 lo4 = make_ushort4(
                f2b(Scf[r][c * 8 + 0]), f2b(Scf[r][c * 8 + 1]),
                f2b(Scf[r][c * 8 + 2]), f2b(Scf[r][c * 8 + 3]));
            ushort4 hi4 = make_ushort4(
                f2b(Scf[r][c * 8 + 4]), f2b(Scf[r][c * 8 + 5]),
                f2b(Scf[r][c * 8 + 6]), f2b(Scf[r][c * 8 + 7]));
            u16* p = (u16*)outp + (size_t)(m0 + r) * 640 + n0 + c * 8;
            *(ushort4*)p = lo4; *(ushort4*)(p + 4) = hi4;
        }
    } else {
#pragma unroll
        for (int i = 0; i < 8; i++) {
            int idx = t + 256 * i, r = idx >> 4, c = idx & 15;  // 128 rows x 16 chunks(4 cols)
            float4 v = *(const float4*)&Scf[r][c * 4];
            *(float4*)((float*)outp + (size_t)(m0 + r) * 640 + n0 + c * 4) = v;
        }
    }
}

// ---------------------------------------------------------------------------
// Launch. Inputs: 0 hidden, 1 cos, 2 sin, 3 mask(UNUSED), 4 Wq, 5 Wk, 6 Wv,
// 7 Wo, 8 q_norm_w, 9 k_norm_w. Workspace (43.3 MB, AO overlays Hb+WT):
//   [0, 16.78M): Hb(10.49M) + WT(1.97M)  -- dead after GEMMs; AO reuses @0
//   [16.78M): WoT 1.31M | Qb 16.78M | Kb 4.19M | Vt_g 4.19M
// ---------------------------------------------------------------------------
extern "C" void kernel_launch(void* const* d_in, const int* in_sizes, int n_in,
                              void* d_out, int out_size, void* d_ws, size_t ws_size,
                              hipStream_t stream) {
    const void* hidden = d_in[0];
    const void* cosT   = d_in[1];
    const void* sinT   = d_in[2];
    const void* Wq     = d_in[4];
    const void* Wk     = d_in[5];
    const void* Wv     = d_in[6];
    const void* Wo     = d_in[7];
    const void* qw     = d_in[8];
    const void* kw     = d_in[9];

    char* ws = (char*)d_ws;
    u16* Hb  = (u16*)ws;                            // 8192*640
    u16* WT  = (u16*)(ws + 10485760);               // 1536*640
    u16* AO  = (u16*)ws;                            // 8192*1024 (overlays Hb/WT)
    u16* WoT = (u16*)(ws + 16777216);               // 640*1024
    u16* Qb  = (u16*)(ws + 18087936);               // 8192*1024
    u16* Kb  = (u16*)(ws + 34865152);               // 8192*256
    u16* Vtg = (u16*)(ws + 39059456);               // 2*256*4096

    prep<<<dim3(4160), 256, 0, stream>>>(hidden, Wq, Wk, Wv, Wo, cosT, Hb, WT, WoT);
    qkv_gemm<<<dim3(12, 64), 256, 0, stream>>>(Hb, WT, Qb, Kb, Vtg);
    norm_rope<<<dim3(8192), 320, 0, stream>>>(Qb, Kb, cosT, sinT, qw, kw);
    attn_mfma<<<dim3(128, 2), 512, 0, stream>>>(Qb, Kb, Vtg, AO);
    out_gemm<<<dim3(10, 64), 256, 0, stream>>>(AO, WoT, cosT, d_out);
}